// Round 11
// baseline (2373.874 us; speedup 1.0000x reference)
//
#include <hip/hip_runtime.h>
#include <hip/hip_fp16.h>
#include <cstddef>
#include <cstdint>

#define B_  256
#define T_  512
#define D_  128
#define H_  256
#define G3_ 768
#define C_  10

typedef _Float16 f16x8 __attribute__((ext_vector_type(8)));
typedef float    f32x4 __attribute__((ext_vector_type(4)));

__device__ __forceinline__ float sigmoid_f(float x) {
    return 1.0f / (1.0f + __expf(-x));
}
__device__ __forceinline__ float tanh_f(float x) {
    return 1.0f - 2.0f / (__expf(2.0f * x) + 1.0f);
}

__device__ __forceinline__ unsigned int packh2(float a, float b) {
    unsigned short lo = __half_as_ushort(__float2half(a));   // k even -> lo16
    unsigned short hi = __half_as_ushort(__float2half(b));   // k odd  -> hi16
    return (unsigned int)lo | ((unsigned int)hi << 16);
}

// ---------------------------------------------------------------------------
// Pack Whh[3H][H] fp32 -> f16 MFMA B-fragment stream for the scan.
// Fragment (w, nt, kt): wave w owns gate-cols c0 = g*256 + w*32 + (nt&1)*16
// (g = nt>>1), K-tile kt. Lane l: n = c0 + (l&15), k = kt*32 + (l>>4)*8 + i.
// (unchanged, harness-verified layout)
// ---------------------------------------------------------------------------
__global__ void k_pack_whh(const float* __restrict__ Whh, uint4* __restrict__ Wl) {
    const int wnt = blockIdx.x;          // w*6 + nt
    const int w  = wnt / 6;
    const int nt = wnt % 6;
    const int t  = threadIdx.x;
    const int kt = t >> 6;
    const int l  = t & 63;
    const int g  = nt >> 1;
    const int n  = g * 256 + w * 32 + (nt & 1) * 16 + (l & 15);
    const int k0 = kt * 32 + (l >> 4) * 8;
    const float* row = Whh + (size_t)n * H_ + k0;
    uint4 u;
    u.x = packh2(row[0], row[1]);
    u.y = packh2(row[2], row[3]);
    u.z = packh2(row[4], row[5]);
    u.w = packh2(row[6], row[7]);
    Wl[(size_t)wnt * 512 + t] = u;
}

// ---------------------------------------------------------------------------
// Pack Wih[768][K] fp32 -> f16 B-fragments for the gi GEMM. (unchanged)
// ---------------------------------------------------------------------------
__global__ void k_pack_wih(const float* __restrict__ W, uint4* __restrict__ Wp,
                           int K) {
    const int KT = K >> 5;
    const int f  = blockIdx.x * 4 + (threadIdx.x >> 6);
    const int l  = threadIdx.x & 63;
    const int ntile = f / KT;
    const int kt    = f - ntile * KT;
    const int n  = ntile * 16 + (l & 15);
    const int k0 = kt * 32 + (l >> 4) * 8;
    const float* row = W + (size_t)n * K + k0;
    uint4 u;
    u.x = packh2(row[0], row[1]);
    u.y = packh2(row[2], row[3]);
    u.z = packh2(row[4], row[5]);
    u.w = packh2(row[6], row[7]);
    Wp[(size_t)f * 64 + l] = u;
}

// ---------------------------------------------------------------------------
// gi GEMM on the matrix pipe: C[M,768] = A[M,K] @ W^T(f16) + bias.
// R11: C is stored F16 (halves the 50 MB/dispatch write stream) and A may be
// F16 (h1c path -- zero added error: the old fp32 h1c was converted to f16
// in-register here anyway). n-tile 128 (R10), C layout NORMAL (row m, col n).
// ---------------------------------------------------------------------------
__global__ __launch_bounds__(256) void k_gemm_f16(
    const void* __restrict__ A, long Abstride, int tcShift, int aIsF16,
    const uint4* __restrict__ Wp,
    const float* __restrict__ bias, _Float16* __restrict__ C,
    int K)
{
    const int tid = threadIdx.x;
    const int w  = tid >> 6;
    const int l  = tid & 63;
    const int c  = l & 15;
    const int g4 = l >> 4;
    const int m0 = blockIdx.y * 128;
    const int n0 = blockIdx.x * 128;
    const int KT = K >> 5;
    const int mask = (1 << tcShift) - 1;

    const int mg0 = m0 + w * 32 + c;
    const int mg1 = mg0 + 16;
    const size_t aoff0 = (size_t)(mg0 >> tcShift) * Abstride
                       + (size_t)(mg0 & mask) * K + g4 * 8;
    const size_t aoff1 = (size_t)(mg1 >> tcShift) * Abstride
                       + (size_t)(mg1 & mask) * K + g4 * 8;
    const float*    Af0 = (const float*)A    + aoff0;
    const float*    Af1 = (const float*)A    + aoff1;
    const _Float16* Ah0 = (const _Float16*)A + aoff0;
    const _Float16* Ah1 = (const _Float16*)A + aoff1;

    const uint4* Wb = Wp + (size_t)((n0 >> 4) * KT) * 64 + l;

    f32x4 acc[2][8] = {};

    for (int kt = 0; kt < KT; kt++) {
        f16x8 a0, a1;
        if (aIsF16) {
            a0 = *(const f16x8*)(Ah0 + kt * 32);
            a1 = *(const f16x8*)(Ah1 + kt * 32);
        } else {
            float4 lo = *(const float4*)(Af0 + kt * 32);
            float4 hi = *(const float4*)(Af0 + kt * 32 + 4);
            a0[0] = (_Float16)lo.x; a0[1] = (_Float16)lo.y;
            a0[2] = (_Float16)lo.z; a0[3] = (_Float16)lo.w;
            a0[4] = (_Float16)hi.x; a0[5] = (_Float16)hi.y;
            a0[6] = (_Float16)hi.z; a0[7] = (_Float16)hi.w;
            lo = *(const float4*)(Af1 + kt * 32);
            hi = *(const float4*)(Af1 + kt * 32 + 4);
            a1[0] = (_Float16)lo.x; a1[1] = (_Float16)lo.y;
            a1[2] = (_Float16)lo.z; a1[3] = (_Float16)lo.w;
            a1[4] = (_Float16)hi.x; a1[5] = (_Float16)hi.y;
            a1[6] = (_Float16)hi.z; a1[7] = (_Float16)hi.w;
        }
#pragma unroll
        for (int ct = 0; ct < 8; ct++) {
            uint4 wf = Wb[(size_t)(ct * KT + kt) * 64];
            acc[0][ct] = __builtin_amdgcn_mfma_f32_16x16x32_f16(
                a0, __builtin_bit_cast(f16x8, wf), acc[0][ct], 0, 0, 0);
            acc[1][ct] = __builtin_amdgcn_mfma_f32_16x16x32_f16(
                a1, __builtin_bit_cast(f16x8, wf), acc[1][ct], 0, 0, 0);
        }
    }

    // D layout: row = tile_row0 + g4*4 + reg, col = tile_col0 + c (verified).
#pragma unroll
    for (int ct = 0; ct < 8; ct++) {
        const int n = n0 + ct * 16 + c;
        const float bv = bias[n];
#pragma unroll
        for (int rt = 0; rt < 2; rt++) {
#pragma unroll
            for (int rg = 0; rg < 4; rg++) {
                const int m = m0 + w * 32 + rt * 16 + g4 * 4 + rg;
                C[(size_t)m * G3_ + n] = (_Float16)(acc[rt][ct][rg] + bv);
            }
        }
    }
}

// ---------------------------------------------------------------------------
// MFMA scan -- EXACT R4 structure (2.92 us/step measured; VGPR 124).
// The allocator's remat-from-L2 of the 32 weight frags per step is the
// cheapest observed weight path for this structure. Closed lines:
//   R2 "+v" @cap256 (AGPR shuttle, 382us) / R3 "+a" pin (hazards, 1145us) /
//   R6 cross-CU split (sync 8.4us/step) / R7 batched+launder (584us) /
//   R9 residency @1wave-SIMD (v0-v255 hard cap, 1248us).
// R11 delta: gi and out_seq are now F16 (scalar u16 loads + cvt; f16 store).
// ---------------------------------------------------------------------------
__device__ __forceinline__ void gru_scan_core(
    const _Float16* __restrict__ gi,   // + b0*Tc*G3   [16 rows][Tc][3H] f16
    const uint4* __restrict__ Wpk,     // [48*8][64] packed B-fragments
    const float* __restrict__ bhh,
    float* __restrict__ h_state,       // + b0*H  (f32)
    _Float16* __restrict__ out_seq,    // + b0*Tc*H or nullptr (f16)
    int Tc, int initZero,
    uint4 (&lds_w)[8192], _Float16 (&lds_h)[2][16][264])
{
    const int tid = threadIdx.x;
    const int w  = tid >> 6;       // wave 0..7
    const int l  = tid & 63;
    const int c  = l & 15;
    const int g4 = l >> 4;         // 0..3

    // ---- stage LDS-resident weight frags (nt 4,5 of every wave) -----------
#pragma unroll
    for (int i = 0; i < 16; i++) {
        int idx = i * 512 + tid;                       // (wv*16 + fl)*64 + ln
        lds_w[idx] = Wpk[(size_t)(idx >> 10) * 3072 + 2048 + (idx & 1023)];
    }

    // ---- register-resident frags: nt 0..3 x kt 0..7 -----------------------
    uint4 wreg[32];
#pragma unroll
    for (int nt = 0; nt < 4; nt++)
#pragma unroll
        for (int kt = 0; kt < 8; kt++)
            wreg[nt * 8 + kt] = Wpk[(size_t)((w * 6 + nt) * 8 + kt) * 64 + l];

    // ---- lane ownership: m = g4*4+r, j = w*32 + jj*16 + c -----------------
    const int jA = w * 32 + c;
    const float br0 = bhh[jA],       br1 = bhh[jA + 16];
    const float bz0 = bhh[256 + jA], bz1 = bhh[256 + jA + 16];
    const float bn0 = bhh[512 + jA], bn1 = bhh[512 + jA + 16];

    float hreg[4][2];
#pragma unroll
    for (int r = 0; r < 4; r++) {
        const int m = g4 * 4 + r;
        if (initZero) {
            hreg[r][0] = 0.0f;
            hreg[r][1] = 0.0f;
        } else {
            hreg[r][0] = h_state[(size_t)m * H_ + jA];
            hreg[r][1] = h_state[(size_t)m * H_ + jA + 16];
        }
        lds_h[0][m][jA]      = (_Float16)hreg[r][0];
        lds_h[0][m][jA + 16] = (_Float16)hreg[r][1];
    }
    __syncthreads();

    int cur = 0;
    for (int tt = 0; tt < Tc; ++tt) {
        // LICM barrier: opaque LDS offset each step.
        unsigned wb = (unsigned)(w * 1024 + l);
        asm volatile("" : "+v"(wb));

        // gi prefetch (f16): issued now, consumed after the MFMA block.
        float gic[4][6];
#pragma unroll
        for (int r = 0; r < 4; r++) {
            const _Float16* gp = gi + ((size_t)(g4 * 4 + r) * Tc + tt) * G3_ + jA;
#pragma unroll
            for (int gg = 0; gg < 3; gg++) {
                gic[r][gg * 2 + 0] = (float)gp[gg * 256];
                gic[r][gg * 2 + 1] = (float)gp[gg * 256 + 16];
            }
        }

        f32x4 acc[6] = {};
#pragma unroll
        for (int kt = 0; kt < 8; kt++) {
            // A-frag: lane supplies h[c][kt*32 + g4*8 .. +8]  (ds_read_b128)
            f16x8 a = *(const f16x8*)&lds_h[cur][c][kt * 32 + g4 * 8];
#pragma unroll
            for (int nt = 0; nt < 4; nt++)
                acc[nt] = __builtin_amdgcn_mfma_f32_16x16x32_f16(
                    a, __builtin_bit_cast(f16x8, wreg[nt * 8 + kt]), acc[nt], 0, 0, 0);
            uint4 u4 = lds_w[wb + kt * 64];            // nt=4 frag
            acc[4] = __builtin_amdgcn_mfma_f32_16x16x32_f16(
                a, __builtin_bit_cast(f16x8, u4), acc[4], 0, 0, 0);
            uint4 u5 = lds_w[wb + (8 + kt) * 64];      // nt=5 frag
            acc[5] = __builtin_amdgcn_mfma_f32_16x16x32_f16(
                a, __builtin_bit_cast(f16x8, u5), acc[5], 0, 0, 0);
        }

        // D layout: row m = g4*4 + reg, col = tile_c0 + c.
        // nt 0/1 = r-gate (jj=0/1), nt 2/3 = z, nt 4/5 = n.
#pragma unroll
        for (int r = 0; r < 4; r++) {
            const int m = g4 * 4 + r;
#pragma unroll
            for (int jj = 0; jj < 2; jj++) {
                float rg = sigmoid_f(gic[r][jj]     + acc[jj][r]     + (jj ? br1 : br0));
                float zg = sigmoid_f(gic[r][2 + jj] + acc[2 + jj][r] + (jj ? bz1 : bz0));
                float ng = tanh_f(gic[r][4 + jj] +
                                  rg * (acc[4 + jj][r] + (jj ? bn1 : bn0)));
                float hn = (1.0f - zg) * ng + zg * hreg[r][jj];
                hreg[r][jj] = hn;
                _Float16 hq = (_Float16)hn;
                lds_h[cur ^ 1][m][jA + jj * 16] = hq;
                if (out_seq)
                    out_seq[((size_t)m * Tc + tt) * H_ + jA + jj * 16] = hq;
            }
        }
        if (tt == Tc - 1) {
#pragma unroll
            for (int r = 0; r < 4; r++) {
                const int m = g4 * 4 + r;
                h_state[(size_t)m * H_ + jA]      = hreg[r][0];
                h_state[(size_t)m * H_ + jA + 16] = hreg[r][1];
            }
        }
        __syncthreads();
        cur ^= 1;
    }
}

// Fused layer-pipelined scan: blocks 0..15 -> layer0 chunk c (16 rows each),
// blocks 16..31 -> layer1 chunk c-1. 148 KB LDS -> 1 block/CU naturally.
__global__ __launch_bounds__(512, 2) void k_gru_scan_fused(
    const _Float16* __restrict__ gi0, const uint4* __restrict__ wl0,
    const float* __restrict__ bhh0, float* __restrict__ hst0,
    _Float16* __restrict__ h1c,
    const _Float16* __restrict__ gi1, const uint4* __restrict__ wl1,
    const float* __restrict__ bhh1, float* __restrict__ hst1,
    int Tc, int do0, int do1, int init0, int init1)
{
    __shared__ __align__(16) uint4    lds_w[8192];        // 128 KB
    __shared__ __align__(16) _Float16 lds_h[2][16][264];  // 16.5 KB

    const int blk = blockIdx.x;
    if (blk < 16) {
        if (!do0) return;
        const int b0 = blk * 16;
        gru_scan_core(gi0 + (size_t)b0 * Tc * G3_, wl0, bhh0,
                      hst0 + (size_t)b0 * H_, h1c + (size_t)b0 * Tc * H_,
                      Tc, init0, lds_w, lds_h);
    } else {
        if (!do1) return;
        const int b0 = (blk - 16) * 16;
        gru_scan_core(gi1 + (size_t)b0 * Tc * G3_, wl1, bhh1,
                      hst1 + (size_t)b0 * H_, nullptr,
                      Tc, init1, lds_w, lds_h);
    }
}

// ---------------------------------------------------------------------------
__global__ void k_fc(const float* __restrict__ h, const float* __restrict__ Wfc,
                     const float* __restrict__ bfc, float* __restrict__ out)
{
    int idx = blockIdx.x * blockDim.x + threadIdx.x;
    if (idx >= B_ * C_) return;
    int b = idx / C_, c = idx % C_;
    const float* hp = h + (size_t)b * H_;
    const float* wp = Wfc + (size_t)c * H_;
    float s = bfc[c];
#pragma unroll 4
    for (int k = 0; k < H_; k++) s = fmaf(hp[k], wp[k], s);
    out[idx] = s;
}

// ---------------------------------------------------------------------------
extern "C" void kernel_launch(void* const* d_in, const int* in_sizes, int n_in,
                              void* d_out, int out_size, void* d_ws, size_t ws_size,
                              hipStream_t stream)
{
    const float* x    = (const float*)d_in[0];
    const float* Wih0 = (const float*)d_in[1];
    const float* Whh0 = (const float*)d_in[2];
    const float* bih0 = (const float*)d_in[3];
    const float* bhh0 = (const float*)d_in[4];
    const float* Wih1 = (const float*)d_in[5];
    const float* Whh1 = (const float*)d_in[6];
    const float* bih1 = (const float*)d_in[7];
    const float* bhh1 = (const float*)d_in[8];
    const float* Wfc  = (const float*)d_in[9];
    const float* bfc  = (const float*)d_in[10];
    float* out = (float*)d_out;

    const size_t wlBytes  = (size_t)48 * 512 * sizeof(uint4);    // 393,216 B
    const size_t wp0Bytes = (size_t)48 * 4 * 64 * sizeof(uint4); // 196,608 B
    const size_t wp1Bytes = (size_t)48 * 8 * 64 * sizeof(uint4); // 393,216 B

    // ---- T-chunk: 64 (pipeline-bubble sweet spot, R10), shrink to fit -----
    const size_t fixedB = 2 * wlBytes + wp0Bytes + wp1Bytes
                        + 2 * (size_t)B_ * H_ * 4 + 16384;
    int Tc = 64, tcShift = 6;
    while (Tc > 1) {
        size_t need = fixedB
                    + 2 * (size_t)B_ * Tc * G3_ * 2    // gi0, gi1 chunks (f16)
                    + (size_t)B_ * Tc * H_ * 2;        // h1 chunk (f16)
        if (need <= ws_size) break;
        Tc >>= 1; tcShift--;
    }
    const int nChunks = T_ / Tc;

    char* ws = (char*)d_ws;
    size_t off = 0;
    auto alloc = [&](size_t bytes) { char* p = ws + off; off += (bytes + 255) & ~(size_t)255; return p; };
    _Float16* gi0 = (_Float16*)alloc((size_t)B_ * Tc * G3_ * 2);
    _Float16* gi1 = (_Float16*)alloc((size_t)B_ * Tc * G3_ * 2);
    _Float16* h1c = (_Float16*)alloc((size_t)B_ * Tc * H_ * 2);
    uint4* wl0  = (uint4*)alloc(wlBytes);
    uint4* wl1  = (uint4*)alloc(wlBytes);
    uint4* wp0  = (uint4*)alloc(wp0Bytes);
    uint4* wp1  = (uint4*)alloc(wp1Bytes);
    float* hst0 = (float*)alloc((size_t)B_ * H_ * 4);
    float* hst1 = (float*)alloc((size_t)B_ * H_ * 4);

    k_pack_whh<<<48, 512, 0, stream>>>(Whh0, wl0);
    k_pack_whh<<<48, 512, 0, stream>>>(Whh1, wl1);
    k_pack_wih<<<48, 256, 0, stream>>>(Wih0, wp0, D_);   // KT=4 -> 192 frags
    k_pack_wih<<<96, 256, 0, stream>>>(Wih1, wp1, H_);   // KT=8 -> 384 frags

    const dim3 ggrid(G3_ / 128, (B_ * Tc) / 128);

    // software pipeline: fused launch c runs scan0(c) and scan1(c-1)
    k_gemm_f16<<<ggrid, 256, 0, stream>>>(
        x, (long)T_ * D_, tcShift, 0, wp0, bih0, gi0, D_);
    k_gru_scan_fused<<<32, 512, 0, stream>>>(
        gi0, wl0, bhh0, hst0, h1c, gi1, wl1, bhh1, hst1,
        Tc, 1, 0, 1, 0);

    for (int c = 1; c < nChunks; ++c) {
        k_gemm_f16<<<ggrid, 256, 0, stream>>>(
            h1c, (long)Tc * H_, tcShift, 1, wp1, bih1, gi1, H_);     // chunk c-1
        k_gemm_f16<<<ggrid, 256, 0, stream>>>(
            x + (size_t)c * Tc * D_, (long)T_ * D_, tcShift, 0, wp0, bih0, gi0, D_);
        k_gru_scan_fused<<<32, 512, 0, stream>>>(
            gi0, wl0, bhh0, hst0, h1c, gi1, wl1, bhh1, hst1,
            Tc, 1, 1, 0, c == 1);
    }

    k_gemm_f16<<<ggrid, 256, 0, stream>>>(
        h1c, (long)Tc * H_, tcShift, 1, wp1, bih1, gi1, H_);         // last chunk
    k_gru_scan_fused<<<32, 512, 0, stream>>>(
        gi0, wl0, bhh0, hst0, h1c, gi1, wl1, bhh1, hst1,
        Tc, 0, 1, 0, nChunks == 1);

    k_fc<<<10, 256, 0, stream>>>(hst1, Wfc, bfc, out);
}

// Round 12
// 2154.538 us; speedup vs baseline: 1.1018x; 1.1018x over previous
//
#include <hip/hip_runtime.h>
#include <hip/hip_fp16.h>
#include <cstddef>
#include <cstdint>

#define B_  256
#define T_  512
#define D_  128
#define H_  256
#define G3_ 768
#define C_  10

typedef _Float16 f16x8 __attribute__((ext_vector_type(8)));
typedef float    f32x4 __attribute__((ext_vector_type(4)));

__device__ __forceinline__ float sigmoid_f(float x) {
    return 1.0f / (1.0f + __expf(-x));
}
__device__ __forceinline__ float tanh_f(float x) {
    return 1.0f - 2.0f / (__expf(2.0f * x) + 1.0f);
}

__device__ __forceinline__ unsigned int packh2(float a, float b) {
    unsigned short lo = __half_as_ushort(__float2half(a));   // k even -> lo16
    unsigned short hi = __half_as_ushort(__float2half(b));   // k odd  -> hi16
    return (unsigned int)lo | ((unsigned int)hi << 16);
}

// ---------------------------------------------------------------------------
// Pack Whh[3H][H] fp32 -> f16 MFMA B-fragment stream for the scan.
// Fragment (w, nt, kt): wave w owns gate-cols c0 = g*256 + w*32 + (nt&1)*16
// (g = nt>>1), K-tile kt. Lane l: n = c0 + (l&15), k = kt*32 + (l>>4)*8 + i.
// (unchanged, harness-verified layout)
// ---------------------------------------------------------------------------
__global__ void k_pack_whh(const float* __restrict__ Whh, uint4* __restrict__ Wl) {
    const int wnt = blockIdx.x;          // w*6 + nt
    const int w  = wnt / 6;
    const int nt = wnt % 6;
    const int t  = threadIdx.x;
    const int kt = t >> 6;
    const int l  = t & 63;
    const int g  = nt >> 1;
    const int n  = g * 256 + w * 32 + (nt & 1) * 16 + (l & 15);
    const int k0 = kt * 32 + (l >> 4) * 8;
    const float* row = Whh + (size_t)n * H_ + k0;
    uint4 u;
    u.x = packh2(row[0], row[1]);
    u.y = packh2(row[2], row[3]);
    u.z = packh2(row[4], row[5]);
    u.w = packh2(row[6], row[7]);
    Wl[(size_t)wnt * 512 + t] = u;
}

// ---------------------------------------------------------------------------
// Pack Wih[768][K] fp32 -> f16 B-fragments for the gi GEMM. (unchanged)
// ---------------------------------------------------------------------------
__global__ void k_pack_wih(const float* __restrict__ W, uint4* __restrict__ Wp,
                           int K) {
    const int KT = K >> 5;
    const int f  = blockIdx.x * 4 + (threadIdx.x >> 6);
    const int l  = threadIdx.x & 63;
    const int ntile = f / KT;
    const int kt    = f - ntile * KT;
    const int n  = ntile * 16 + (l & 15);
    const int k0 = kt * 32 + (l >> 4) * 8;
    const float* row = W + (size_t)n * K + k0;
    uint4 u;
    u.x = packh2(row[0], row[1]);
    u.y = packh2(row[2], row[3]);
    u.z = packh2(row[4], row[5]);
    u.w = packh2(row[6], row[7]);
    Wp[(size_t)f * 64 + l] = u;
}

// ---------------------------------------------------------------------------
// gi GEMM on the matrix pipe: C[M,768](f32) = A[M,K] @ W^T(f16) + bias.
// R12: C back to F32 (R11's f16 gi made the scan's per-step loads slower --
// d16 load + cvt chain; scan is latency-bound, not BW-bound). A may be F16
// (h1c path -- zero added error, halves layer-1 A-read). n-tile 128 (R10).
// ---------------------------------------------------------------------------
__global__ __launch_bounds__(256) void k_gemm_f16(
    const void* __restrict__ A, long Abstride, int tcShift, int aIsF16,
    const uint4* __restrict__ Wp,
    const float* __restrict__ bias, float* __restrict__ C,
    int K)
{
    const int tid = threadIdx.x;
    const int w  = tid >> 6;
    const int l  = tid & 63;
    const int c  = l & 15;
    const int g4 = l >> 4;
    const int m0 = blockIdx.y * 128;
    const int n0 = blockIdx.x * 128;
    const int KT = K >> 5;
    const int mask = (1 << tcShift) - 1;

    const int mg0 = m0 + w * 32 + c;
    const int mg1 = mg0 + 16;
    const size_t aoff0 = (size_t)(mg0 >> tcShift) * Abstride
                       + (size_t)(mg0 & mask) * K + g4 * 8;
    const size_t aoff1 = (size_t)(mg1 >> tcShift) * Abstride
                       + (size_t)(mg1 & mask) * K + g4 * 8;
    const float*    Af0 = (const float*)A    + aoff0;
    const float*    Af1 = (const float*)A    + aoff1;
    const _Float16* Ah0 = (const _Float16*)A + aoff0;
    const _Float16* Ah1 = (const _Float16*)A + aoff1;

    const uint4* Wb = Wp + (size_t)((n0 >> 4) * KT) * 64 + l;

    f32x4 acc[2][8] = {};

    for (int kt = 0; kt < KT; kt++) {
        f16x8 a0, a1;
        if (aIsF16) {
            a0 = *(const f16x8*)(Ah0 + kt * 32);
            a1 = *(const f16x8*)(Ah1 + kt * 32);
        } else {
            float4 lo = *(const float4*)(Af0 + kt * 32);
            float4 hi = *(const float4*)(Af0 + kt * 32 + 4);
            a0[0] = (_Float16)lo.x; a0[1] = (_Float16)lo.y;
            a0[2] = (_Float16)lo.z; a0[3] = (_Float16)lo.w;
            a0[4] = (_Float16)hi.x; a0[5] = (_Float16)hi.y;
            a0[6] = (_Float16)hi.z; a0[7] = (_Float16)hi.w;
            lo = *(const float4*)(Af1 + kt * 32);
            hi = *(const float4*)(Af1 + kt * 32 + 4);
            a1[0] = (_Float16)lo.x; a1[1] = (_Float16)lo.y;
            a1[2] = (_Float16)lo.z; a1[3] = (_Float16)lo.w;
            a1[4] = (_Float16)hi.x; a1[5] = (_Float16)hi.y;
            a1[6] = (_Float16)hi.z; a1[7] = (_Float16)hi.w;
        }
#pragma unroll
        for (int ct = 0; ct < 8; ct++) {
            uint4 wf = Wb[(size_t)(ct * KT + kt) * 64];
            acc[0][ct] = __builtin_amdgcn_mfma_f32_16x16x32_f16(
                a0, __builtin_bit_cast(f16x8, wf), acc[0][ct], 0, 0, 0);
            acc[1][ct] = __builtin_amdgcn_mfma_f32_16x16x32_f16(
                a1, __builtin_bit_cast(f16x8, wf), acc[1][ct], 0, 0, 0);
        }
    }

    // D layout: row = tile_row0 + g4*4 + reg, col = tile_col0 + c (verified).
#pragma unroll
    for (int ct = 0; ct < 8; ct++) {
        const int n = n0 + ct * 16 + c;
        const float bv = bias[n];
#pragma unroll
        for (int rt = 0; rt < 2; rt++) {
#pragma unroll
            for (int rg = 0; rg < 4; rg++) {
                const int m = m0 + w * 32 + rt * 16 + g4 * 4 + rg;
                C[(size_t)m * G3_ + n] = acc[rt][ct][rg] + bv;
            }
        }
    }
}

// ---------------------------------------------------------------------------
// MFMA scan -- EXACT R4/R10 structure (2.92 us/step, 187 us @ Tc=64; VGPR
// 124). The allocator's remat-from-L2 of the 32 weight frags per step is the
// cheapest observed weight path for this structure. Closed lines:
//   R2 "+v" @cap256 (AGPR shuttle, 382us) / R3 "+a" pin (hazards, 1145us) /
//   R6 cross-CU split (sync 8.4us/step) / R7 batched+launder (584us) /
//   R9 residency @1wave-SIMD (v0-v255 hard cap, 1248us) /
//   R11 gi-f16 (d16 load + cvt chain, +0.4us/step -- scan is latency-bound,
//   byte-halving gi does NOT pay).
// gi is F32. out_seq (h1c) is F16: store-only change off the dependency
// chain; feeds the layer-1 GEMM A-path where f16 is exact.
// ---------------------------------------------------------------------------
__device__ __forceinline__ void gru_scan_core(
    const float* __restrict__ gi,      // + b0*Tc*G3   [16 rows][Tc][3H] f32
    const uint4* __restrict__ Wpk,     // [48*8][64] packed B-fragments
    const float* __restrict__ bhh,
    float* __restrict__ h_state,       // + b0*H  (f32)
    _Float16* __restrict__ out_seq,    // + b0*Tc*H or nullptr (f16)
    int Tc, int initZero,
    uint4 (&lds_w)[8192], _Float16 (&lds_h)[2][16][264])
{
    const int tid = threadIdx.x;
    const int w  = tid >> 6;       // wave 0..7
    const int l  = tid & 63;
    const int c  = l & 15;
    const int g4 = l >> 4;         // 0..3

    // ---- stage LDS-resident weight frags (nt 4,5 of every wave) -----------
#pragma unroll
    for (int i = 0; i < 16; i++) {
        int idx = i * 512 + tid;                       // (wv*16 + fl)*64 + ln
        lds_w[idx] = Wpk[(size_t)(idx >> 10) * 3072 + 2048 + (idx & 1023)];
    }

    // ---- register-resident frags: nt 0..3 x kt 0..7 -----------------------
    uint4 wreg[32];
#pragma unroll
    for (int nt = 0; nt < 4; nt++)
#pragma unroll
        for (int kt = 0; kt < 8; kt++)
            wreg[nt * 8 + kt] = Wpk[(size_t)((w * 6 + nt) * 8 + kt) * 64 + l];

    // ---- lane ownership: m = g4*4+r, j = w*32 + jj*16 + c -----------------
    const int jA = w * 32 + c;
    const float br0 = bhh[jA],       br1 = bhh[jA + 16];
    const float bz0 = bhh[256 + jA], bz1 = bhh[256 + jA + 16];
    const float bn0 = bhh[512 + jA], bn1 = bhh[512 + jA + 16];

    float hreg[4][2];
#pragma unroll
    for (int r = 0; r < 4; r++) {
        const int m = g4 * 4 + r;
        if (initZero) {
            hreg[r][0] = 0.0f;
            hreg[r][1] = 0.0f;
        } else {
            hreg[r][0] = h_state[(size_t)m * H_ + jA];
            hreg[r][1] = h_state[(size_t)m * H_ + jA + 16];
        }
        lds_h[0][m][jA]      = (_Float16)hreg[r][0];
        lds_h[0][m][jA + 16] = (_Float16)hreg[r][1];
    }
    __syncthreads();

    int cur = 0;
    for (int tt = 0; tt < Tc; ++tt) {
        // LICM barrier: opaque LDS offset each step.
        unsigned wb = (unsigned)(w * 1024 + l);
        asm volatile("" : "+v"(wb));

        // gi prefetch (f32): issued now, consumed after the MFMA block.
        float gic[4][6];
#pragma unroll
        for (int r = 0; r < 4; r++) {
            const float* gp = gi + ((size_t)(g4 * 4 + r) * Tc + tt) * G3_ + jA;
#pragma unroll
            for (int gg = 0; gg < 3; gg++) {
                gic[r][gg * 2 + 0] = gp[gg * 256];
                gic[r][gg * 2 + 1] = gp[gg * 256 + 16];
            }
        }

        f32x4 acc[6] = {};
#pragma unroll
        for (int kt = 0; kt < 8; kt++) {
            // A-frag: lane supplies h[c][kt*32 + g4*8 .. +8]  (ds_read_b128)
            f16x8 a = *(const f16x8*)&lds_h[cur][c][kt * 32 + g4 * 8];
#pragma unroll
            for (int nt = 0; nt < 4; nt++)
                acc[nt] = __builtin_amdgcn_mfma_f32_16x16x32_f16(
                    a, __builtin_bit_cast(f16x8, wreg[nt * 8 + kt]), acc[nt], 0, 0, 0);
            uint4 u4 = lds_w[wb + kt * 64];            // nt=4 frag
            acc[4] = __builtin_amdgcn_mfma_f32_16x16x32_f16(
                a, __builtin_bit_cast(f16x8, u4), acc[4], 0, 0, 0);
            uint4 u5 = lds_w[wb + (8 + kt) * 64];      // nt=5 frag
            acc[5] = __builtin_amdgcn_mfma_f32_16x16x32_f16(
                a, __builtin_bit_cast(f16x8, u5), acc[5], 0, 0, 0);
        }

        // D layout: row m = g4*4 + reg, col = tile_c0 + c.
        // nt 0/1 = r-gate (jj=0/1), nt 2/3 = z, nt 4/5 = n.
#pragma unroll
        for (int r = 0; r < 4; r++) {
            const int m = g4 * 4 + r;
#pragma unroll
            for (int jj = 0; jj < 2; jj++) {
                float rg = sigmoid_f(gic[r][jj]     + acc[jj][r]     + (jj ? br1 : br0));
                float zg = sigmoid_f(gic[r][2 + jj] + acc[2 + jj][r] + (jj ? bz1 : bz0));
                float ng = tanh_f(gic[r][4 + jj] +
                                  rg * (acc[4 + jj][r] + (jj ? bn1 : bn0)));
                float hn = (1.0f - zg) * ng + zg * hreg[r][jj];
                hreg[r][jj] = hn;
                _Float16 hq = (_Float16)hn;
                lds_h[cur ^ 1][m][jA + jj * 16] = hq;
                if (out_seq)
                    out_seq[((size_t)m * Tc + tt) * H_ + jA + jj * 16] = hq;
            }
        }
        if (tt == Tc - 1) {
#pragma unroll
            for (int r = 0; r < 4; r++) {
                const int m = g4 * 4 + r;
                h_state[(size_t)m * H_ + jA]      = hreg[r][0];
                h_state[(size_t)m * H_ + jA + 16] = hreg[r][1];
            }
        }
        __syncthreads();
        cur ^= 1;
    }
}

// Fused layer-pipelined scan: blocks 0..15 -> layer0 chunk c (16 rows each),
// blocks 16..31 -> layer1 chunk c-1. 148 KB LDS -> 1 block/CU naturally.
__global__ __launch_bounds__(512, 2) void k_gru_scan_fused(
    const float* __restrict__ gi0, const uint4* __restrict__ wl0,
    const float* __restrict__ bhh0, float* __restrict__ hst0,
    _Float16* __restrict__ h1c,
    const float* __restrict__ gi1, const uint4* __restrict__ wl1,
    const float* __restrict__ bhh1, float* __restrict__ hst1,
    int Tc, int do0, int do1, int init0, int init1)
{
    __shared__ __align__(16) uint4    lds_w[8192];        // 128 KB
    __shared__ __align__(16) _Float16 lds_h[2][16][264];  // 16.5 KB

    const int blk = blockIdx.x;
    if (blk < 16) {
        if (!do0) return;
        const int b0 = blk * 16;
        gru_scan_core(gi0 + (size_t)b0 * Tc * G3_, wl0, bhh0,
                      hst0 + (size_t)b0 * H_, h1c + (size_t)b0 * Tc * H_,
                      Tc, init0, lds_w, lds_h);
    } else {
        if (!do1) return;
        const int b0 = (blk - 16) * 16;
        gru_scan_core(gi1 + (size_t)b0 * Tc * G3_, wl1, bhh1,
                      hst1 + (size_t)b0 * H_, nullptr,
                      Tc, init1, lds_w, lds_h);
    }
}

// ---------------------------------------------------------------------------
__global__ void k_fc(const float* __restrict__ h, const float* __restrict__ Wfc,
                     const float* __restrict__ bfc, float* __restrict__ out)
{
    int idx = blockIdx.x * blockDim.x + threadIdx.x;
    if (idx >= B_ * C_) return;
    int b = idx / C_, c = idx % C_;
    const float* hp = h + (size_t)b * H_;
    const float* wp = Wfc + (size_t)c * H_;
    float s = bfc[c];
#pragma unroll 4
    for (int k = 0; k < H_; k++) s = fmaf(hp[k], wp[k], s);
    out[idx] = s;
}

// ---------------------------------------------------------------------------
extern "C" void kernel_launch(void* const* d_in, const int* in_sizes, int n_in,
                              void* d_out, int out_size, void* d_ws, size_t ws_size,
                              hipStream_t stream)
{
    const float* x    = (const float*)d_in[0];
    const float* Wih0 = (const float*)d_in[1];
    const float* Whh0 = (const float*)d_in[2];
    const float* bih0 = (const float*)d_in[3];
    const float* bhh0 = (const float*)d_in[4];
    const float* Wih1 = (const float*)d_in[5];
    const float* Whh1 = (const float*)d_in[6];
    const float* bih1 = (const float*)d_in[7];
    const float* bhh1 = (const float*)d_in[8];
    const float* Wfc  = (const float*)d_in[9];
    const float* bfc  = (const float*)d_in[10];
    float* out = (float*)d_out;

    const size_t wlBytes  = (size_t)48 * 512 * sizeof(uint4);    // 393,216 B
    const size_t wp0Bytes = (size_t)48 * 4 * 64 * sizeof(uint4); // 196,608 B
    const size_t wp1Bytes = (size_t)48 * 8 * 64 * sizeof(uint4); // 393,216 B

    // ---- T-chunk: 64 (pipeline-bubble sweet spot, R10), shrink to fit -----
    const size_t fixedB = 2 * wlBytes + wp0Bytes + wp1Bytes
                        + 2 * (size_t)B_ * H_ * 4 + 16384;
    int Tc = 64, tcShift = 6;
    while (Tc > 1) {
        size_t need = fixedB
                    + 2 * (size_t)B_ * Tc * G3_ * 4    // gi0, gi1 chunks (f32)
                    + (size_t)B_ * Tc * H_ * 2;        // h1 chunk (f16)
        if (need <= ws_size) break;
        Tc >>= 1; tcShift--;
    }
    const int nChunks = T_ / Tc;

    char* ws = (char*)d_ws;
    size_t off = 0;
    auto alloc = [&](size_t bytes) { char* p = ws + off; off += (bytes + 255) & ~(size_t)255; return p; };
    float*    gi0 = (float*)alloc((size_t)B_ * Tc * G3_ * 4);
    float*    gi1 = (float*)alloc((size_t)B_ * Tc * G3_ * 4);
    _Float16* h1c = (_Float16*)alloc((size_t)B_ * Tc * H_ * 2);
    uint4* wl0  = (uint4*)alloc(wlBytes);
    uint4* wl1  = (uint4*)alloc(wlBytes);
    uint4* wp0  = (uint4*)alloc(wp0Bytes);
    uint4* wp1  = (uint4*)alloc(wp1Bytes);
    float* hst0 = (float*)alloc((size_t)B_ * H_ * 4);
    float* hst1 = (float*)alloc((size_t)B_ * H_ * 4);

    k_pack_whh<<<48, 512, 0, stream>>>(Whh0, wl0);
    k_pack_whh<<<48, 512, 0, stream>>>(Whh1, wl1);
    k_pack_wih<<<48, 256, 0, stream>>>(Wih0, wp0, D_);   // KT=4 -> 192 frags
    k_pack_wih<<<96, 256, 0, stream>>>(Wih1, wp1, H_);   // KT=8 -> 384 frags

    const dim3 ggrid(G3_ / 128, (B_ * Tc) / 128);

    // software pipeline: fused launch c runs scan0(c) and scan1(c-1)
    k_gemm_f16<<<ggrid, 256, 0, stream>>>(
        x, (long)T_ * D_, tcShift, 0, wp0, bih0, gi0, D_);
    k_gru_scan_fused<<<32, 512, 0, stream>>>(
        gi0, wl0, bhh0, hst0, h1c, gi1, wl1, bhh1, hst1,
        Tc, 1, 0, 1, 0);

    for (int c = 1; c < nChunks; ++c) {
        k_gemm_f16<<<ggrid, 256, 0, stream>>>(
            h1c, (long)Tc * H_, tcShift, 1, wp1, bih1, gi1, H_);     // chunk c-1
        k_gemm_f16<<<ggrid, 256, 0, stream>>>(
            x + (size_t)c * Tc * D_, (long)T_ * D_, tcShift, 0, wp0, bih0, gi0, D_);
        k_gru_scan_fused<<<32, 512, 0, stream>>>(
            gi0, wl0, bhh0, hst0, h1c, gi1, wl1, bhh1, hst1,
            Tc, 1, 1, 0, c == 1);
    }

    k_gemm_f16<<<ggrid, 256, 0, stream>>>(
        h1c, (long)Tc * H_, tcShift, 1, wp1, bih1, gi1, H_);         // last chunk
    k_gru_scan_fused<<<32, 512, 0, stream>>>(
        gi0, wl0, bhh0, hst0, h1c, gi1, wl1, bhh1, hst1,
        Tc, 0, 1, 0, nChunks == 1);

    k_fc<<<10, 256, 0, stream>>>(hst1, Wfc, bfc, out);
}

// Round 13
// 1996.963 us; speedup vs baseline: 1.1887x; 1.0789x over previous
//
#include <hip/hip_runtime.h>
#include <hip/hip_fp16.h>
#include <cstddef>
#include <cstdint>

#define B_  256
#define T_  512
#define D_  128
#define H_  256
#define G3_ 768
#define C_  10

typedef _Float16 f16x8 __attribute__((ext_vector_type(8)));
typedef float    f32x4 __attribute__((ext_vector_type(4)));

__device__ __forceinline__ float sigmoid_f(float x) {
    return 1.0f / (1.0f + __expf(-x));
}
__device__ __forceinline__ float tanh_f(float x) {
    return 1.0f - 2.0f / (__expf(2.0f * x) + 1.0f);
}

__device__ __forceinline__ unsigned int packh2(float a, float b) {
    unsigned short lo = __half_as_ushort(__float2half(a));   // k even -> lo16
    unsigned short hi = __half_as_ushort(__float2half(b));   // k odd  -> hi16
    return (unsigned int)lo | ((unsigned int)hi << 16);
}

// ---------------------------------------------------------------------------
// Pack Whh[3H][H] fp32 -> f16 MFMA B-fragment stream for the scan.
// (unchanged, harness-verified layout)
// ---------------------------------------------------------------------------
__global__ void k_pack_whh(const float* __restrict__ Whh, uint4* __restrict__ Wl) {
    const int wnt = blockIdx.x;          // w*6 + nt
    const int w  = wnt / 6;
    const int nt = wnt % 6;
    const int t  = threadIdx.x;
    const int kt = t >> 6;
    const int l  = t & 63;
    const int g  = nt >> 1;
    const int n  = g * 256 + w * 32 + (nt & 1) * 16 + (l & 15);
    const int k0 = kt * 32 + (l >> 4) * 8;
    const float* row = Whh + (size_t)n * H_ + k0;
    uint4 u;
    u.x = packh2(row[0], row[1]);
    u.y = packh2(row[2], row[3]);
    u.z = packh2(row[4], row[5]);
    u.w = packh2(row[6], row[7]);
    Wl[(size_t)wnt * 512 + t] = u;
}

// ---------------------------------------------------------------------------
// Pack Wih[768][K] fp32 -> f16 B-fragments for the gi GEMM. (unchanged)
// ---------------------------------------------------------------------------
__global__ void k_pack_wih(const float* __restrict__ W, uint4* __restrict__ Wp,
                           int K) {
    const int KT = K >> 5;
    const int f  = blockIdx.x * 4 + (threadIdx.x >> 6);
    const int l  = threadIdx.x & 63;
    const int ntile = f / KT;
    const int kt    = f - ntile * KT;
    const int n  = ntile * 16 + (l & 15);
    const int k0 = kt * 32 + (l >> 4) * 8;
    const float* row = W + (size_t)n * K + k0;
    uint4 u;
    u.x = packh2(row[0], row[1]);
    u.y = packh2(row[2], row[3]);
    u.z = packh2(row[4], row[5]);
    u.w = packh2(row[6], row[7]);
    Wp[(size_t)f * 64 + l] = u;
}

// ---------------------------------------------------------------------------
// Standalone gi GEMM (matrix pipe): used for gemm0(chunk 0) and all gemm1.
// C f32, A f32 or f16 (h1c). n-tile 128 (R10). (unchanged from R12)
// ---------------------------------------------------------------------------
__global__ __launch_bounds__(256) void k_gemm_f16(
    const void* __restrict__ A, long Abstride, int tcShift, int aIsF16,
    const uint4* __restrict__ Wp,
    const float* __restrict__ bias, float* __restrict__ C,
    int K)
{
    const int tid = threadIdx.x;
    const int w  = tid >> 6;
    const int l  = tid & 63;
    const int c  = l & 15;
    const int g4 = l >> 4;
    const int m0 = blockIdx.y * 128;
    const int n0 = blockIdx.x * 128;
    const int KT = K >> 5;
    const int mask = (1 << tcShift) - 1;

    const int mg0 = m0 + w * 32 + c;
    const int mg1 = mg0 + 16;
    const size_t aoff0 = (size_t)(mg0 >> tcShift) * Abstride
                       + (size_t)(mg0 & mask) * K + g4 * 8;
    const size_t aoff1 = (size_t)(mg1 >> tcShift) * Abstride
                       + (size_t)(mg1 & mask) * K + g4 * 8;
    const float*    Af0 = (const float*)A    + aoff0;
    const float*    Af1 = (const float*)A    + aoff1;
    const _Float16* Ah0 = (const _Float16*)A + aoff0;
    const _Float16* Ah1 = (const _Float16*)A + aoff1;

    const uint4* Wb = Wp + (size_t)((n0 >> 4) * KT) * 64 + l;

    f32x4 acc[2][8] = {};

    for (int kt = 0; kt < KT; kt++) {
        f16x8 a0, a1;
        if (aIsF16) {
            a0 = *(const f16x8*)(Ah0 + kt * 32);
            a1 = *(const f16x8*)(Ah1 + kt * 32);
        } else {
            float4 lo = *(const float4*)(Af0 + kt * 32);
            float4 hi = *(const float4*)(Af0 + kt * 32 + 4);
            a0[0] = (_Float16)lo.x; a0[1] = (_Float16)lo.y;
            a0[2] = (_Float16)lo.z; a0[3] = (_Float16)lo.w;
            a0[4] = (_Float16)hi.x; a0[5] = (_Float16)hi.y;
            a0[6] = (_Float16)hi.z; a0[7] = (_Float16)hi.w;
            lo = *(const float4*)(Af1 + kt * 32);
            hi = *(const float4*)(Af1 + kt * 32 + 4);
            a1[0] = (_Float16)lo.x; a1[1] = (_Float16)lo.y;
            a1[2] = (_Float16)lo.z; a1[3] = (_Float16)lo.w;
            a1[4] = (_Float16)hi.x; a1[5] = (_Float16)hi.y;
            a1[6] = (_Float16)hi.z; a1[7] = (_Float16)hi.w;
        }
#pragma unroll
        for (int ct = 0; ct < 8; ct++) {
            uint4 wf = Wb[(size_t)(ct * KT + kt) * 64];
            acc[0][ct] = __builtin_amdgcn_mfma_f32_16x16x32_f16(
                a0, __builtin_bit_cast(f16x8, wf), acc[0][ct], 0, 0, 0);
            acc[1][ct] = __builtin_amdgcn_mfma_f32_16x16x32_f16(
                a1, __builtin_bit_cast(f16x8, wf), acc[1][ct], 0, 0, 0);
        }
    }

    // D layout: row = tile_row0 + g4*4 + reg, col = tile_col0 + c (verified).
#pragma unroll
    for (int ct = 0; ct < 8; ct++) {
        const int n = n0 + ct * 16 + c;
        const float bv = bias[n];
#pragma unroll
        for (int rt = 0; rt < 2; rt++) {
#pragma unroll
            for (int rg = 0; rg < 4; rg++) {
                const int m = m0 + w * 32 + rt * 16 + g4 * 4 + rg;
                C[(size_t)m * G3_ + n] = acc[rt][ct][rg] + bv;
            }
        }
    }
}

// ---------------------------------------------------------------------------
// MFMA scan -- EXACT R4/R10 structure (2.92 us/step, 187 us @ Tc=64; VGPR
// 124). Closed lines: R2/R3/R6/R7/R9 register-residency & cross-CU variants,
// R11 gi-f16 (latency-bound scan, byte-halving loses to the cvt chain).
// gi F32; out_seq (h1c) F16 (store-only, exact for the layer-1 GEMM).
// ---------------------------------------------------------------------------
__device__ __forceinline__ void gru_scan_core(
    const float* __restrict__ gi,      // + b0*Tc*G3   [16 rows][Tc][3H] f32
    const uint4* __restrict__ Wpk,     // [48*8][64] packed B-fragments
    const float* __restrict__ bhh,
    float* __restrict__ h_state,       // + b0*H  (f32)
    _Float16* __restrict__ out_seq,    // + b0*Tc*H or nullptr (f16)
    int Tc, int initZero,
    uint4 (&lds_w)[8192], _Float16 (&lds_h)[2][16][264])
{
    const int tid = threadIdx.x;
    const int w  = tid >> 6;       // wave 0..7
    const int l  = tid & 63;
    const int c  = l & 15;
    const int g4 = l >> 4;         // 0..3

    // ---- stage LDS-resident weight frags (nt 4,5 of every wave) -----------
#pragma unroll
    for (int i = 0; i < 16; i++) {
        int idx = i * 512 + tid;                       // (wv*16 + fl)*64 + ln
        lds_w[idx] = Wpk[(size_t)(idx >> 10) * 3072 + 2048 + (idx & 1023)];
    }

    // ---- register-resident frags: nt 0..3 x kt 0..7 -----------------------
    uint4 wreg[32];
#pragma unroll
    for (int nt = 0; nt < 4; nt++)
#pragma unroll
        for (int kt = 0; kt < 8; kt++)
            wreg[nt * 8 + kt] = Wpk[(size_t)((w * 6 + nt) * 8 + kt) * 64 + l];

    // ---- lane ownership: m = g4*4+r, j = w*32 + jj*16 + c -----------------
    const int jA = w * 32 + c;
    const float br0 = bhh[jA],       br1 = bhh[jA + 16];
    const float bz0 = bhh[256 + jA], bz1 = bhh[256 + jA + 16];
    const float bn0 = bhh[512 + jA], bn1 = bhh[512 + jA + 16];

    float hreg[4][2];
#pragma unroll
    for (int r = 0; r < 4; r++) {
        const int m = g4 * 4 + r;
        if (initZero) {
            hreg[r][0] = 0.0f;
            hreg[r][1] = 0.0f;
        } else {
            hreg[r][0] = h_state[(size_t)m * H_ + jA];
            hreg[r][1] = h_state[(size_t)m * H_ + jA + 16];
        }
        lds_h[0][m][jA]      = (_Float16)hreg[r][0];
        lds_h[0][m][jA + 16] = (_Float16)hreg[r][1];
    }
    __syncthreads();

    int cur = 0;
    for (int tt = 0; tt < Tc; ++tt) {
        // LICM barrier: opaque LDS offset each step.
        unsigned wb = (unsigned)(w * 1024 + l);
        asm volatile("" : "+v"(wb));

        // gi prefetch (f32): issued now, consumed after the MFMA block.
        float gic[4][6];
#pragma unroll
        for (int r = 0; r < 4; r++) {
            const float* gp = gi + ((size_t)(g4 * 4 + r) * Tc + tt) * G3_ + jA;
#pragma unroll
            for (int gg = 0; gg < 3; gg++) {
                gic[r][gg * 2 + 0] = gp[gg * 256];
                gic[r][gg * 2 + 1] = gp[gg * 256 + 16];
            }
        }

        f32x4 acc[6] = {};
#pragma unroll
        for (int kt = 0; kt < 8; kt++) {
            // A-frag: lane supplies h[c][kt*32 + g4*8 .. +8]  (ds_read_b128)
            f16x8 a = *(const f16x8*)&lds_h[cur][c][kt * 32 + g4 * 8];
#pragma unroll
            for (int nt = 0; nt < 4; nt++)
                acc[nt] = __builtin_amdgcn_mfma_f32_16x16x32_f16(
                    a, __builtin_bit_cast(f16x8, wreg[nt * 8 + kt]), acc[nt], 0, 0, 0);
            uint4 u4 = lds_w[wb + kt * 64];            // nt=4 frag
            acc[4] = __builtin_amdgcn_mfma_f32_16x16x32_f16(
                a, __builtin_bit_cast(f16x8, u4), acc[4], 0, 0, 0);
            uint4 u5 = lds_w[wb + (8 + kt) * 64];      // nt=5 frag
            acc[5] = __builtin_amdgcn_mfma_f32_16x16x32_f16(
                a, __builtin_bit_cast(f16x8, u5), acc[5], 0, 0, 0);
        }

        // D layout: row m = g4*4 + reg, col = tile_c0 + c.
        // nt 0/1 = r-gate (jj=0/1), nt 2/3 = z, nt 4/5 = n.
#pragma unroll
        for (int r = 0; r < 4; r++) {
            const int m = g4 * 4 + r;
#pragma unroll
            for (int jj = 0; jj < 2; jj++) {
                float rg = sigmoid_f(gic[r][jj]     + acc[jj][r]     + (jj ? br1 : br0));
                float zg = sigmoid_f(gic[r][2 + jj] + acc[2 + jj][r] + (jj ? bz1 : bz0));
                float ng = tanh_f(gic[r][4 + jj] +
                                  rg * (acc[4 + jj][r] + (jj ? bn1 : bn0)));
                float hn = (1.0f - zg) * ng + zg * hreg[r][jj];
                hreg[r][jj] = hn;
                _Float16 hq = (_Float16)hn;
                lds_h[cur ^ 1][m][jA + jj * 16] = hq;
                if (out_seq)
                    out_seq[((size_t)m * Tc + tt) * H_ + jA + jj * 16] = hq;
            }
        }
        if (tt == Tc - 1) {
#pragma unroll
            for (int r = 0; r < 4; r++) {
                const int m = g4 * 4 + r;
                h_state[(size_t)m * H_ + jA]      = hreg[r][0];
                h_state[(size_t)m * H_ + jA + 16] = hreg[r][1];
            }
        }
        __syncthreads();
        cur ^= 1;
    }
}

// ---------------------------------------------------------------------------
// Fused launch, R13: blocks 0..15 scan layer0 chunk c; 16..31 scan layer1
// chunk c-1 (as before, 32 CUs); blocks >= 32 run gemm0(c+1) = x @ Wih0 into
// the OTHER gi0 buffer on the 224 idle CUs. NO cross-block dependency exists
// inside the launch (gemm0 depends only on x; its output is consumed by the
// NEXT stream-ordered launch) -- this is pure co-residency, not R6-style
// sync. gemm blocks: 512 thr = 8 waves, m-tile 256, n-tile 128, K=128.
// ---------------------------------------------------------------------------
__global__ __launch_bounds__(512, 2) void k_gru_scan_fused(
    const float* __restrict__ gi0, const uint4* __restrict__ wl0,
    const float* __restrict__ bhh0, float* __restrict__ hst0,
    _Float16* __restrict__ h1c,
    const float* __restrict__ gi1, const uint4* __restrict__ wl1,
    const float* __restrict__ bhh1, float* __restrict__ hst1,
    int Tc, int do0, int do1, int init0, int init1,
    const float* __restrict__ gx, const uint4* __restrict__ wp0,
    const float* __restrict__ bih0, float* __restrict__ gi0n,
    int doGemm, int tcShift)
{
    __shared__ __align__(16) uint4    lds_w[8192];        // 128 KB
    __shared__ __align__(16) _Float16 lds_h[2][16][264];  // 16.5 KB

    const int blk = blockIdx.x;
    if (blk < 16) {
        if (!do0) return;
        const int b0 = blk * 16;
        gru_scan_core(gi0 + (size_t)b0 * Tc * G3_, wl0, bhh0,
                      hst0 + (size_t)b0 * H_, h1c + (size_t)b0 * Tc * H_,
                      Tc, init0, lds_w, lds_h);
    } else if (blk < 32) {
        if (!do1) return;
        const int b0 = (blk - 16) * 16;
        gru_scan_core(gi1 + (size_t)b0 * Tc * G3_, wl1, bhh1,
                      hst1 + (size_t)b0 * H_, nullptr,
                      Tc, init1, lds_w, lds_h);
    } else {
        // ---- co-scheduled gemm0(c+1): no dependency on this launch --------
        if (!doGemm) return;
        const int gb = blk - 32;
        const int tid = threadIdx.x;
        const int w  = tid >> 6;
        const int l  = tid & 63;
        const int c  = l & 15;
        const int g4 = l >> 4;
        const int n0 = (gb % 6) * 128;
        const int m0 = (gb / 6) * 256 + w * 32;
        const int mask = (1 << tcShift) - 1;

        const int mg0 = m0 + c;
        const int mg1 = mg0 + 16;
        const float* Af0 = gx + (size_t)(mg0 >> tcShift) * (T_ * D_)
                              + (size_t)(mg0 & mask) * D_ + g4 * 8;
        const float* Af1 = gx + (size_t)(mg1 >> tcShift) * (T_ * D_)
                              + (size_t)(mg1 & mask) * D_ + g4 * 8;
        const uint4* Wb = wp0 + (size_t)((n0 >> 4) * 4) * 64 + l;   // KT=4

        f32x4 acc[2][8] = {};
#pragma unroll
        for (int kt = 0; kt < 4; kt++) {
            f16x8 a0, a1;
            {
                float4 lo = *(const float4*)(Af0 + kt * 32);
                float4 hi = *(const float4*)(Af0 + kt * 32 + 4);
                a0[0] = (_Float16)lo.x; a0[1] = (_Float16)lo.y;
                a0[2] = (_Float16)lo.z; a0[3] = (_Float16)lo.w;
                a0[4] = (_Float16)hi.x; a0[5] = (_Float16)hi.y;
                a0[6] = (_Float16)hi.z; a0[7] = (_Float16)hi.w;
                lo = *(const float4*)(Af1 + kt * 32);
                hi = *(const float4*)(Af1 + kt * 32 + 4);
                a1[0] = (_Float16)lo.x; a1[1] = (_Float16)lo.y;
                a1[2] = (_Float16)lo.z; a1[3] = (_Float16)lo.w;
                a1[4] = (_Float16)hi.x; a1[5] = (_Float16)hi.y;
                a1[6] = (_Float16)hi.z; a1[7] = (_Float16)hi.w;
            }
#pragma unroll
            for (int ct = 0; ct < 8; ct++) {
                uint4 wf = Wb[(size_t)(ct * 4 + kt) * 64];
                acc[0][ct] = __builtin_amdgcn_mfma_f32_16x16x32_f16(
                    a0, __builtin_bit_cast(f16x8, wf), acc[0][ct], 0, 0, 0);
                acc[1][ct] = __builtin_amdgcn_mfma_f32_16x16x32_f16(
                    a1, __builtin_bit_cast(f16x8, wf), acc[1][ct], 0, 0, 0);
            }
        }
#pragma unroll
        for (int ct = 0; ct < 8; ct++) {
            const int n = n0 + ct * 16 + c;
            const float bv = bih0[n];
#pragma unroll
            for (int rt = 0; rt < 2; rt++) {
#pragma unroll
                for (int rg = 0; rg < 4; rg++) {
                    const int m = m0 + rt * 16 + g4 * 4 + rg;
                    gi0n[(size_t)m * G3_ + n] = acc[rt][ct][rg] + bv;
                }
            }
        }
    }
}

// ---------------------------------------------------------------------------
__global__ void k_fc(const float* __restrict__ h, const float* __restrict__ Wfc,
                     const float* __restrict__ bfc, float* __restrict__ out)
{
    int idx = blockIdx.x * blockDim.x + threadIdx.x;
    if (idx >= B_ * C_) return;
    int b = idx / C_, c = idx % C_;
    const float* hp = h + (size_t)b * H_;
    const float* wp = Wfc + (size_t)c * H_;
    float s = bfc[c];
#pragma unroll 4
    for (int k = 0; k < H_; k++) s = fmaf(hp[k], wp[k], s);
    out[idx] = s;
}

// ---------------------------------------------------------------------------
extern "C" void kernel_launch(void* const* d_in, const int* in_sizes, int n_in,
                              void* d_out, int out_size, void* d_ws, size_t ws_size,
                              hipStream_t stream)
{
    const float* x    = (const float*)d_in[0];
    const float* Wih0 = (const float*)d_in[1];
    const float* Whh0 = (const float*)d_in[2];
    const float* bih0 = (const float*)d_in[3];
    const float* bhh0 = (const float*)d_in[4];
    const float* Wih1 = (const float*)d_in[5];
    const float* Whh1 = (const float*)d_in[6];
    const float* bih1 = (const float*)d_in[7];
    const float* bhh1 = (const float*)d_in[8];
    const float* Wfc  = (const float*)d_in[9];
    const float* bfc  = (const float*)d_in[10];
    float* out = (float*)d_out;

    const size_t wlBytes  = (size_t)48 * 512 * sizeof(uint4);    // 393,216 B
    const size_t wp0Bytes = (size_t)48 * 4 * 64 * sizeof(uint4); // 196,608 B
    const size_t wp1Bytes = (size_t)48 * 8 * 64 * sizeof(uint4); // 393,216 B

    // ---- T-chunk: 64 (R10 sweet spot); 3 gi buffers now (gi0 dbuf + gi1) --
    const size_t fixedB = 2 * wlBytes + wp0Bytes + wp1Bytes
                        + 2 * (size_t)B_ * H_ * 4 + 16384;
    int Tc = 64, tcShift = 6;
    while (Tc > 1) {
        size_t need = fixedB
                    + 3 * (size_t)B_ * Tc * G3_ * 4    // gi0a, gi0b, gi1 (f32)
                    + (size_t)B_ * Tc * H_ * 2;        // h1 chunk (f16)
        if (need <= ws_size) break;
        Tc >>= 1; tcShift--;
    }
    const int nChunks = T_ / Tc;

    char* ws = (char*)d_ws;
    size_t off = 0;
    auto alloc = [&](size_t bytes) { char* p = ws + off; off += (bytes + 255) & ~(size_t)255; return p; };
    float*    gi0a = (float*)alloc((size_t)B_ * Tc * G3_ * 4);
    float*    gi0b = (float*)alloc((size_t)B_ * Tc * G3_ * 4);
    float*    gi1  = (float*)alloc((size_t)B_ * Tc * G3_ * 4);
    _Float16* h1c  = (_Float16*)alloc((size_t)B_ * Tc * H_ * 2);
    uint4* wl0  = (uint4*)alloc(wlBytes);
    uint4* wl1  = (uint4*)alloc(wlBytes);
    uint4* wp0  = (uint4*)alloc(wp0Bytes);
    uint4* wp1  = (uint4*)alloc(wp1Bytes);
    float* hst0 = (float*)alloc((size_t)B_ * H_ * 4);
    float* hst1 = (float*)alloc((size_t)B_ * H_ * 4);

    float* gi0buf[2] = { gi0a, gi0b };

    k_pack_whh<<<48, 512, 0, stream>>>(Whh0, wl0);
    k_pack_whh<<<48, 512, 0, stream>>>(Whh1, wl1);
    k_pack_wih<<<48, 256, 0, stream>>>(Wih0, wp0, D_);   // KT=4 -> 192 frags
    k_pack_wih<<<96, 256, 0, stream>>>(Wih1, wp1, H_);   // KT=8 -> 384 frags

    const dim3 ggrid(G3_ / 128, (B_ * Tc) / 128);
    const int NG = 32 + 6 * ((B_ * Tc) / 256);           // scan + gemm blocks

    // gemm0(0) standalone; thereafter gemm0(c+1) rides inside scan launch c.
    k_gemm_f16<<<ggrid, 256, 0, stream>>>(
        x, (long)T_ * D_, tcShift, 0, wp0, bih0, gi0buf[0], D_);
    k_gru_scan_fused<<<NG, 512, 0, stream>>>(
        gi0buf[0], wl0, bhh0, hst0, h1c, gi1, wl1, bhh1, hst1,
        Tc, 1, 0, 1, 0,
        x + (size_t)1 * Tc * D_, wp0, bih0, gi0buf[1], nChunks > 1, tcShift);

    for (int c = 1; c < nChunks; ++c) {
        k_gemm_f16<<<ggrid, 256, 0, stream>>>(
            h1c, (long)Tc * H_, tcShift, 1, wp1, bih1, gi1, H_);     // gemm1(c-1)
        k_gru_scan_fused<<<NG, 512, 0, stream>>>(
            gi0buf[c & 1], wl0, bhh0, hst0, h1c, gi1, wl1, bhh1, hst1,
            Tc, 1, 1, 0, c == 1,
            x + (size_t)(c + 1) * Tc * D_, wp0, bih0, gi0buf[(c + 1) & 1],
            c + 1 < nChunks, tcShift);
    }

    k_gemm_f16<<<ggrid, 256, 0, stream>>>(
        h1c, (long)Tc * H_, tcShift, 1, wp1, bih1, gi1, H_);         // gemm1(last)
    k_gru_scan_fused<<<NG, 512, 0, stream>>>(
        gi0buf[0], wl0, bhh0, hst0, h1c, gi1, wl1, bhh1, hst1,
        Tc, 0, 1, 0, nChunks == 1,
        x, wp0, bih0, gi0buf[1], 0, tcShift);                        // scan1 only

    k_fc<<<10, 256, 0, stream>>>(hst1, Wfc, bfc, out);
}